// Round 4
// baseline (742.465 us; speedup 1.0000x reference)
//
#include <hip/hip_runtime.h>
#include <math.h>

#define NPERSEG 30
#define STEPW 15
#define NSEG 3
#define NF 16
#define PATCH 60
#define STRIDE 30
#define NP_ROW 199
#define NBATCH 1024
#define T_LEN 6000
#define NPATCH_TOTAL (NBATCH * NP_ROW)   /* 203776 */
#define GB 32
#define NBLK_B (NPATCH_TOTAL / GB)       /* 6368 */

// f64 twiddles cos/sin(2*pi*m/30), correctly-rounded decimal literals.
constexpr double TC[30] = {
  1.0,
  0.97814760073380563793,
  0.91354545764260089550,
  0.80901699437494742410,
  0.66913060635885821383,
  0.5,
  0.30901699437494742410,
  0.10452846326765347140,
 -0.10452846326765347140,
 -0.30901699437494742410,
 -0.5,
 -0.66913060635885821383,
 -0.80901699437494742410,
 -0.91354545764260089550,
 -0.97814760073380563793,
 -1.0,
 -0.97814760073380563793,
 -0.91354545764260089550,
 -0.80901699437494742410,
 -0.66913060635885821383,
 -0.5,
 -0.30901699437494742410,
 -0.10452846326765347140,
  0.10452846326765347140,
  0.30901699437494742410,
  0.5,
  0.66913060635885821383,
  0.80901699437494742410,
  0.91354545764260089550,
  0.97814760073380563793,
};
constexpr double TS[30] = {
  0.0,
  0.20791169081775933710,
  0.40673664307580020775,
  0.58778525229247312917,
  0.74314482547739423501,
  0.86602540378443864676,
  0.95105651629515357212,
  0.99452189536827333692,
  0.99452189536827333692,
  0.95105651629515357212,
  0.86602540378443864676,
  0.74314482547739423501,
  0.58778525229247312917,
  0.40673664307580020775,
  0.20791169081775933710,
  0.0,
 -0.20791169081775933710,
 -0.40673664307580020775,
 -0.58778525229247312917,
 -0.74314482547739423501,
 -0.86602540378443864676,
 -0.95105651629515357212,
 -0.99452189536827333692,
 -0.99452189536827333692,
 -0.95105651629515357212,
 -0.86602540378443864676,
 -0.74314482547739423501,
 -0.58778525229247312917,
 -0.40673664307580020775,
 -0.20791169081775933710,
};
// WIN_NORM = 200 * sum(hann^2) = 2250 exactly (periodic hann, N=30).
constexpr double INV_WN = 1.0 / 2250.0;
constexpr double THIRD  = 1.0 / 3.0;

// numpy's pairwise f32 sum for n=30
__device__ __forceinline__ float np_sum30_f32(const float* a) {
    float r[8];
#pragma unroll
    for (int j = 0; j < 8; ++j) r[j] = a[j];
#pragma unroll
    for (int i = 8; i < 24; i += 8)
#pragma unroll
        for (int j = 0; j < 8; ++j) r[j] += a[i + j];
    float res = ((r[0] + r[1]) + (r[2] + r[3])) + ((r[4] + r[5]) + (r[6] + r[7]));
#pragma unroll
    for (int i = 24; i < 30; ++i) res += a[i];
    return res;
}

// numpy pairwise f64 sum for n=16
__device__ __forceinline__ double np_sum16_f64(const double* a) {
    double r[8];
#pragma unroll
    for (int j = 0; j < 8; ++j) r[j] = a[j] + a[8 + j];
    return ((r[0] + r[1]) + (r[2] + r[3])) + ((r[4] + r[5]) + (r[6] + r[7]));
}

// ===================== Kernel A: per-patch features (f64) =====================
// One block = one batch row. Row staged into LDS with coalesced float4 loads
// (each x byte fetched from HBM exactly once); one thread = one patch computes
// from LDS (2-4 way bank aliasing only). Features written block-compact:
// patch p's 22 floats at out[(p>>5)*8192 + (p&31)*22] — contiguous inside each
// 32-patch MLP group, read back (and then overwritten) only by mlp block p>>5.
// All arithmetic is bit-identical to the verified round-2 feature phase.
__global__ __launch_bounds__(256, 4) void feat_kernel(
    const float* __restrict__ x,
    const float* __restrict__ g_m, const float* __restrict__ b_m,
    const float* __restrict__ g_s, const float* __restrict__ b_s,
    float* __restrict__ out)
{
    __shared__ float xs[T_LEN];

    const int tid = threadIdx.x;
    const int row = blockIdx.x;

    {
        const float4* src = reinterpret_cast<const float4*>(x + (size_t)row * T_LEN);
        float4* dst = reinterpret_cast<float4*>(xs);
        for (int i = tid; i < T_LEN / 4; i += 256) dst[i] = src[i];
    }
    __syncthreads();
    if (tid >= NP_ROW) return;

    const float* pf = xs + tid * STRIDE;
    float f[22];

    // ---- morph (f64 continuous; discrete decisions input-exact) ----
    double morph[13];
    {
        double vmax = (double)pf[0], vmin = vmax, vsum = 0.0;
#pragma unroll
        for (int n = 0; n < PATCH; ++n) {
            double v = (double)pf[n];
            vmax = fmax(vmax, v); vmin = fmin(vmin, v); vsum += v;
        }
        double vmean = vsum / 60.0;
        double s2 = 0.0, s3 = 0.0, s4 = 0.0, ssq = 0.0;
#pragma unroll
        for (int n = 0; n < PATCH; ++n) {
            double v = (double)pf[n];
            double c = v - vmean, c2 = c * c;
            s2 += c2; s3 += c2 * c; s4 += c2 * c2;
            ssq += v * v;
        }
        double m2 = s2 / 60.0, m3 = s3 / 60.0, m4 = s4 / 60.0;
        double vstd = sqrt(m2);

        int amax = 0; float aval = fabsf(pf[0]);
#pragma unroll
        for (int n = 1; n < PATCH; ++n) {
            float a = fabsf(pf[n]);
            if (a > aval) { aval = a; amax = n; }
        }
        double peak_loc = (double)((float)amax / 60.0f);

        double dmax = (double)pf[1] - (double)pf[0], dmin = dmax, dabssum = 0.0;
#pragma unroll
        for (int n = 0; n < PATCH - 1; ++n) {
            double d = (double)pf[n + 1] - (double)pf[n];
            dmax = fmax(dmax, d); dmin = fmin(dmin, d); dabssum += fabs(d);
        }
        double dabsmean = dabssum / 59.0;

        int zc = 0;
        {
            float v0 = pf[0] + 1e-10f;
            int prev = (v0 > 0.0f) - (v0 < 0.0f);
#pragma unroll
            for (int n = 1; n < PATCH; ++n) {
                float v = pf[n] + 1e-10f;
                int s = (v > 0.0f) - (v < 0.0f);
                if (s != prev) zc++;
                prev = s;
            }
        }
        double zcf = (double)zc / 60.0;
        double kurt = m4 / (m2 * m2) - 3.0;
        double skew = m3 / (m2 * sqrt(m2));

        morph[0] = vmax;  morph[1] = vmin;  morph[2] = vmax - vmin;
        morph[3] = vmean; morph[4] = vstd;  morph[5] = peak_loc;
        morph[6] = dmax;  morph[7] = dmin;  morph[8] = dabsmean;
        morph[9] = zcf;   morph[10] = ssq;  morph[11] = kurt; morph[12] = skew;
#pragma unroll
        for (int i = 0; i < 13; ++i) if (!isfinite(morph[i])) morph[i] = 0.0;
    }
    // morph group layernorm (f64) -> f[0..12]
    {
        double mu = 0.0;
#pragma unroll
        for (int i = 0; i < 13; ++i) mu += morph[i];
        mu /= 13.0;
        double var = 0.0;
#pragma unroll
        for (int i = 0; i < 13; ++i) { double d = morph[i] - mu; var += d * d; }
        var /= 13.0;
        double inv = 1.0 / sqrt(var + 1e-5);
#pragma unroll
        for (int i = 0; i < 13; ++i)
            f[i] = (float)((morph[i] - mu) * inv * (double)g_m[i] + (double)b_m[i]);
    }

    // ---- Welch PSD: f32 windowing, f64 symmetric DFT, literal twiddles ----
    double psd[NF];
#pragma unroll
    for (int k = 0; k < NF; ++k) psd[k] = 0.0;

#pragma unroll
    for (int s = 0; s < NSEG; ++s) {
        float q[NPERSEG];
#pragma unroll
        for (int n = 0; n < NPERSEG; ++n) q[n] = pf[s * STEPW + n];

        float res = np_sum30_f32(q);
        float smean = res / 30.0f;
        float y[NPERSEG];
#pragma unroll
        for (int n = 0; n < NPERSEG; ++n) {
            const float hn = (float)(0.5 * (1.0 - TC[n]));
            y[n] = (q[n] - smean) * hn;
        }

        double y0  = (double)y[0];
        double y15 = (double)y[15];
        double u[15], v[15];
#pragma unroll
        for (int m = 1; m < 15; ++m) {
            double a = (double)y[m], b = (double)y[NPERSEG - m];
            u[m] = a + b;
            v[m] = a - b;
        }

#pragma unroll
        for (int k = 0; k < NF; ++k) {
            double re = (k & 1) ? (y0 - y15) : (y0 + y15);
            double im = 0.0;
#pragma unroll
            for (int m = 1; m < 15; ++m) {
                const double tcv = TC[(k * m) % 30];
                const double tsv = TS[(k * m) % 30];
                re += u[m] * tcv;
                if (tsv != 0.0) im += v[m] * tsv;
            }
            double pw = re * re + im * im;
            pw *= INV_WN;
            if (k != 0 && k != NF - 1) pw = pw + pw;
            psd[k] += pw;
        }
    }
#pragma unroll
    for (int k = 0; k < NF; ++k) psd[k] = psd[k] * THIRD;

    // ---- spectral features, f64 ----
    double total = np_sum16_f64(psd) + 1e-12;
    double invt = 1.0 / total;

    double band1 = psd[1] * invt;
    double band3 = ((psd[2] + psd[3]) + psd[4]) * invt;
    double b4s = 0.0;
#pragma unroll
    for (int k = 5; k <= 14; ++k) b4s += psd[k];
    double band4 = b4s * invt;

    int bk = 0; double bpv = psd[0];
#pragma unroll
    for (int k = 1; k < NF; ++k) if (psd[k] > bpv) { bpv = psd[k]; bk = k; }

    double th = 0.95 * total;
    int ek = 0;
    {
        double acc = 0.0; bool found = false;
#pragma unroll
        for (int k = 0; k < NF; ++k) {
            acc += psd[k];
            if (!found && acc >= th) { ek = k; found = true; }
        }
    }

    double ent = 0.0;
#pragma unroll
    for (int k = 0; k < NF; ++k) {
        double pn = psd[k] * invt;
        ent -= pn * log2(pn + 1e-12);
    }

    double spec[9];
    spec[0] = 0.0;
    spec[1] = band1;
    spec[2] = 0.0;
    spec[3] = band3;
    spec[4] = band4;
    spec[5] = (double)((float)((double)bk * 200.0 / 30.0));
    spec[6] = (double)((float)((double)ek * 200.0 / 30.0));
    spec[7] = ent;
    spec[8] = total;
#pragma unroll
    for (int i = 0; i < 9; ++i) if (!isfinite(spec[i])) spec[i] = 0.0;

    // spec group layernorm (f64) -> f[13..21]
    {
        double mu = 0.0;
#pragma unroll
        for (int i = 0; i < 9; ++i) mu += spec[i];
        mu /= 9.0;
        double var = 0.0;
#pragma unroll
        for (int i = 0; i < 9; ++i) { double d = spec[i] - mu; var += d * d; }
        var /= 9.0;
        double inv = 1.0 / sqrt(var + 1e-5);
#pragma unroll
        for (int i = 0; i < 9; ++i)
            f[13 + i] = (float)((spec[i] - mu) * inv * (double)g_s[i] + (double)b_s[i]);
    }

    // ---- block-compact feature store (contiguous within each 32-patch group) ----
    const int p = row * NP_ROW + tid;
    float* op = out + (size_t)(p >> 5) * (GB * 256) + (size_t)(p & 31) * 22;
#pragma unroll
    for (int i = 0; i < 11; ++i)
        *reinterpret_cast<float2*>(op + 2 * i) = make_float2(f[2 * i], f[2 * i + 1]);
}

// ===================== Kernel B: MLP (f32) =====================
// One block = 32 patches. Channel map ch = 4*(tid&63)+c so W2/b2/g_o/b_o/out
// are all float4 accesses (4x fewer VMEM instrs than scalar). Wave wv owns
// patches 8*wv..8*wv+7 and all 256 channels for them -> output layernorm is a
// single in-wave shuffle reduction. Per-accumulator k-order (k ascending,
// kk 0..3 inside each chunk) is unchanged -> W2 GEMM bit-identical.
__global__ __launch_bounds__(256, 6) void mlp_kernel(
    const float* __restrict__ W1, const float* __restrict__ b1,
    const float* __restrict__ W2, const float* __restrict__ b2,
    const float* __restrict__ g_o, const float* __restrict__ b_o,
    float* __restrict__ out)
{
    __shared__ float Fsl[GB * 22];     // 704 floats
    __shared__ float Hs[GB][128];

    const int tid = threadIdx.x;
    const size_t base = (size_t)blockIdx.x * (GB * 256);

    // stage this block's compact feature slab (176 float4 = 704 floats)
    if (tid < 176)
        reinterpret_cast<float4*>(Fsl)[tid] =
            *reinterpret_cast<const float4*>(out + base + 4 * (size_t)tid);
    __syncthreads();

    // ---- W1 + exact gelu -> Hs ----
    {
        const int hc  = tid & 127;
        const int ppb = tid >> 7;
        float w1c[22];
#pragma unroll
        for (int k = 0; k < 22; ++k) w1c[k] = W1[k * 128 + hc];
        const float b1v = b1[hc];
#pragma unroll
        for (int v = 0; v < 16; ++v) {
            const int pp = ppb + 2 * v;
            float a = b1v;
#pragma unroll
            for (int k = 0; k < 22; ++k) a += Fsl[pp * 22 + k] * w1c[k];
            Hs[pp][hc] = 0.5f * a * (1.0f + erff(a * 0.70710678118654752440f));
        }
    }
    __syncthreads();

    // ---- W2 GEMM: thread owns 4 consecutive channels x 8 patches ----
    const int cb = tid & 63;
    const int wv = tid >> 6;

    float4 acc[8];
    {
        const float4 b2v = *reinterpret_cast<const float4*>(b2 + 4 * cb);
#pragma unroll
        for (int p = 0; p < 8; ++p) acc[p] = b2v;
    }

#pragma unroll 2
    for (int k = 0; k < 128; k += 4) {
        float4 w0 = *reinterpret_cast<const float4*>(&W2[(k + 0) * 256 + 4 * cb]);
        float4 w1 = *reinterpret_cast<const float4*>(&W2[(k + 1) * 256 + 4 * cb]);
        float4 w2 = *reinterpret_cast<const float4*>(&W2[(k + 2) * 256 + 4 * cb]);
        float4 w3 = *reinterpret_cast<const float4*>(&W2[(k + 3) * 256 + 4 * cb]);
#pragma unroll
        for (int p = 0; p < 8; ++p) {
            const float4 h = *reinterpret_cast<const float4*>(&Hs[8 * wv + p][k]);
            // k-ascending FMA order per accumulator (bit-identical to verified)
            acc[p].x += h.x * w0.x; acc[p].y += h.x * w0.y;
            acc[p].z += h.x * w0.z; acc[p].w += h.x * w0.w;
            acc[p].x += h.y * w1.x; acc[p].y += h.y * w1.y;
            acc[p].z += h.y * w1.z; acc[p].w += h.y * w1.w;
            acc[p].x += h.z * w2.x; acc[p].y += h.z * w2.y;
            acc[p].z += h.z * w2.z; acc[p].w += h.z * w2.w;
            acc[p].x += h.w * w3.x; acc[p].y += h.w * w3.y;
            acc[p].z += h.w * w3.z; acc[p].w += h.w * w3.w;
        }
    }

    // ---- 256-ch layernorm: in-wave reduction, float4 store ----
    const float4 go4 = *reinterpret_cast<const float4*>(g_o + 4 * cb);
    const float4 bo4 = *reinterpret_cast<const float4*>(b_o + 4 * cb);
#pragma unroll
    for (int p = 0; p < 8; ++p) {
        float s = (acc[p].x + acc[p].y) + (acc[p].z + acc[p].w);
        float q = (acc[p].x * acc[p].x + acc[p].y * acc[p].y)
                + (acc[p].z * acc[p].z + acc[p].w * acc[p].w);
        for (int off = 32; off; off >>= 1) {
            s += __shfl_xor(s, off);
            q += __shfl_xor(q, off);
        }
        const float mu  = s * (1.0f / 256.0f);
        const float var = q * (1.0f / 256.0f) - mu * mu;
        const float inv = rsqrtf(var + 1e-5f);
        float4 o;
        o.x = (acc[p].x - mu) * inv * go4.x + bo4.x;
        o.y = (acc[p].y - mu) * inv * go4.y + bo4.y;
        o.z = (acc[p].z - mu) * inv * go4.z + bo4.z;
        o.w = (acc[p].w - mu) * inv * go4.w + bo4.w;
        *reinterpret_cast<float4*>(out + base + (size_t)(8 * wv + p) * 256 + 4 * cb) = o;
    }
}

extern "C" void kernel_launch(void* const* d_in, const int* in_sizes, int n_in,
                              void* d_out, int out_size, void* d_ws, size_t ws_size,
                              hipStream_t stream) {
    const float* x   = (const float*)d_in[0];
    const float* g_m = (const float*)d_in[1];
    const float* b_m = (const float*)d_in[2];
    const float* g_s = (const float*)d_in[3];
    const float* b_s = (const float*)d_in[4];
    const float* W1  = (const float*)d_in[5];
    const float* b1  = (const float*)d_in[6];
    const float* W2  = (const float*)d_in[7];
    const float* b2  = (const float*)d_in[8];
    const float* g_o = (const float*)d_in[9];
    const float* b_o = (const float*)d_in[10];
    float* out = (float*)d_out;

    feat_kernel<<<NBATCH, 256, 0, stream>>>(x, g_m, b_m, g_s, b_s, out);
    mlp_kernel<<<NBLK_B, 256, 0, stream>>>(W1, b1, W2, b2, g_o, b_o, out);
}

// Round 5
// 509.868 us; speedup vs baseline: 1.4562x; 1.4562x over previous
//
#include <hip/hip_runtime.h>
#include <math.h>

#define NPERSEG 30
#define STEPW 15
#define NSEG 3
#define NF 16
#define PATCH 60
#define STRIDE 30
#define NP_ROW 199
#define NBATCH 1024
#define T_LEN 6000
#define NPATCH_TOTAL (NBATCH * NP_ROW)   /* 203776 */
#define GB 32
#define NBLK_B (NPATCH_TOTAL / GB)       /* 6368 */

// f64 twiddles cos/sin(2*pi*m/30), correctly-rounded decimal literals.
constexpr double TC[30] = {
  1.0,
  0.97814760073380563793,
  0.91354545764260089550,
  0.80901699437494742410,
  0.66913060635885821383,
  0.5,
  0.30901699437494742410,
  0.10452846326765347140,
 -0.10452846326765347140,
 -0.30901699437494742410,
 -0.5,
 -0.66913060635885821383,
 -0.80901699437494742410,
 -0.91354545764260089550,
 -0.97814760073380563793,
 -1.0,
 -0.97814760073380563793,
 -0.91354545764260089550,
 -0.80901699437494742410,
 -0.66913060635885821383,
 -0.5,
 -0.30901699437494742410,
 -0.10452846326765347140,
  0.10452846326765347140,
  0.30901699437494742410,
  0.5,
  0.66913060635885821383,
  0.80901699437494742410,
  0.91354545764260089550,
  0.97814760073380563793,
};
constexpr double TS[30] = {
  0.0,
  0.20791169081775933710,
  0.40673664307580020775,
  0.58778525229247312917,
  0.74314482547739423501,
  0.86602540378443864676,
  0.95105651629515357212,
  0.99452189536827333692,
  0.99452189536827333692,
  0.95105651629515357212,
  0.86602540378443864676,
  0.74314482547739423501,
  0.58778525229247312917,
  0.40673664307580020775,
  0.20791169081775933710,
  0.0,
 -0.20791169081775933710,
 -0.40673664307580020775,
 -0.58778525229247312917,
 -0.74314482547739423501,
 -0.86602540378443864676,
 -0.95105651629515357212,
 -0.99452189536827333692,
 -0.99452189536827333692,
 -0.95105651629515357212,
 -0.86602540378443864676,
 -0.74314482547739423501,
 -0.58778525229247312917,
 -0.40673664307580020775,
 -0.20791169081775933710,
};
// WIN_NORM = 200 * sum(hann^2) = 2250 exactly (periodic hann, N=30).
constexpr double INV_WN = 1.0 / 2250.0;
constexpr double THIRD  = 1.0 / 3.0;

// numpy's pairwise f32 sum for n=30
__device__ __forceinline__ float np_sum30_f32(const float* a) {
    float r[8];
#pragma unroll
    for (int j = 0; j < 8; ++j) r[j] = a[j];
#pragma unroll
    for (int i = 8; i < 24; i += 8)
#pragma unroll
        for (int j = 0; j < 8; ++j) r[j] += a[i + j];
    float res = ((r[0] + r[1]) + (r[2] + r[3])) + ((r[4] + r[5]) + (r[6] + r[7]));
#pragma unroll
    for (int i = 24; i < 30; ++i) res += a[i];
    return res;
}

// numpy pairwise f64 sum for n=16
__device__ __forceinline__ double np_sum16_f64(const double* a) {
    double r[8];
#pragma unroll
    for (int j = 0; j < 8; ++j) r[j] = a[j] + a[8 + j];
    return ((r[0] + r[1]) + (r[2] + r[3])) + ((r[4] + r[5]) + (r[6] + r[7]));
}

// ===================== Kernel A: per-patch features (f64) =====================
// One block = one batch row, row staged in LDS (x fetched from HBM once).
// NO launch-bounds occupancy minimum: the DFT needs ~150 live VGPRs; capping
// the allocator (rounds 1-4) caused scratch spills = 100s of MB of TCC traffic
// (round-4 PMC: VGPR=64, FETCH 326MB, WRITE 494MB, VALUBusy 10%).
// Segment loop is unroll-1 to keep the per-seg working set bounded.
// All arithmetic bit-identical to the round-4 kernel (passed, absmax 0.015625).
__global__ __launch_bounds__(256) void feat_kernel(
    const float* __restrict__ x,
    const float* __restrict__ g_m, const float* __restrict__ b_m,
    const float* __restrict__ g_s, const float* __restrict__ b_s,
    float* __restrict__ out)
{
    __shared__ float xs[T_LEN];

    const int tid = threadIdx.x;
    const int row = blockIdx.x;

    {
        const float4* src = reinterpret_cast<const float4*>(x + (size_t)row * T_LEN);
        float4* dst = reinterpret_cast<float4*>(xs);
        for (int i = tid; i < T_LEN / 4; i += 256) dst[i] = src[i];
    }
    __syncthreads();
    if (tid >= NP_ROW) return;

    const float* pf = xs + tid * STRIDE;
    float f[22];

    // ---- morph (f64 continuous; discrete decisions input-exact) ----
    double morph[13];
    {
        double vmax = (double)pf[0], vmin = vmax, vsum = 0.0;
#pragma unroll
        for (int n = 0; n < PATCH; ++n) {
            double v = (double)pf[n];
            vmax = fmax(vmax, v); vmin = fmin(vmin, v); vsum += v;
        }
        double vmean = vsum / 60.0;
        double s2 = 0.0, s3 = 0.0, s4 = 0.0, ssq = 0.0;
#pragma unroll
        for (int n = 0; n < PATCH; ++n) {
            double v = (double)pf[n];
            double c = v - vmean, c2 = c * c;
            s2 += c2; s3 += c2 * c; s4 += c2 * c2;
            ssq += v * v;
        }
        double m2 = s2 / 60.0, m3 = s3 / 60.0, m4 = s4 / 60.0;
        double vstd = sqrt(m2);

        int amax = 0; float aval = fabsf(pf[0]);
#pragma unroll
        for (int n = 1; n < PATCH; ++n) {
            float a = fabsf(pf[n]);
            if (a > aval) { aval = a; amax = n; }
        }
        double peak_loc = (double)((float)amax / 60.0f);

        double dmax = (double)pf[1] - (double)pf[0], dmin = dmax, dabssum = 0.0;
#pragma unroll
        for (int n = 0; n < PATCH - 1; ++n) {
            double d = (double)pf[n + 1] - (double)pf[n];
            dmax = fmax(dmax, d); dmin = fmin(dmin, d); dabssum += fabs(d);
        }
        double dabsmean = dabssum / 59.0;

        int zc = 0;
        {
            float v0 = pf[0] + 1e-10f;
            int prev = (v0 > 0.0f) - (v0 < 0.0f);
#pragma unroll
            for (int n = 1; n < PATCH; ++n) {
                float v = pf[n] + 1e-10f;
                int s = (v > 0.0f) - (v < 0.0f);
                if (s != prev) zc++;
                prev = s;
            }
        }
        double zcf = (double)zc / 60.0;
        double kurt = m4 / (m2 * m2) - 3.0;
        double skew = m3 / (m2 * sqrt(m2));

        morph[0] = vmax;  morph[1] = vmin;  morph[2] = vmax - vmin;
        morph[3] = vmean; morph[4] = vstd;  morph[5] = peak_loc;
        morph[6] = dmax;  morph[7] = dmin;  morph[8] = dabsmean;
        morph[9] = zcf;   morph[10] = ssq;  morph[11] = kurt; morph[12] = skew;
#pragma unroll
        for (int i = 0; i < 13; ++i) if (!isfinite(morph[i])) morph[i] = 0.0;
    }
    // morph group layernorm (f64) -> f[0..12]
    {
        double mu = 0.0;
#pragma unroll
        for (int i = 0; i < 13; ++i) mu += morph[i];
        mu /= 13.0;
        double var = 0.0;
#pragma unroll
        for (int i = 0; i < 13; ++i) { double d = morph[i] - mu; var += d * d; }
        var /= 13.0;
        double inv = 1.0 / sqrt(var + 1e-5);
#pragma unroll
        for (int i = 0; i < 13; ++i)
            f[i] = (float)((morph[i] - mu) * inv * (double)g_m[i] + (double)b_m[i]);
    }

    // ---- Welch PSD: f32 windowing, f64 symmetric DFT, literal twiddles ----
    double psd[NF];
#pragma unroll
    for (int k = 0; k < NF; ++k) psd[k] = 0.0;

#pragma unroll 1
    for (int s = 0; s < NSEG; ++s) {
        float q[NPERSEG];
#pragma unroll
        for (int n = 0; n < NPERSEG; ++n) q[n] = pf[s * STEPW + n];

        float res = np_sum30_f32(q);
        float smean = res / 30.0f;
        float y[NPERSEG];
#pragma unroll
        for (int n = 0; n < NPERSEG; ++n) {
            const float hn = (float)(0.5 * (1.0 - TC[n]));
            y[n] = (q[n] - smean) * hn;
        }

        double y0  = (double)y[0];
        double y15 = (double)y[15];
        double u[15], v[15];
#pragma unroll
        for (int m = 1; m < 15; ++m) {
            double a = (double)y[m], b = (double)y[NPERSEG - m];
            u[m] = a + b;
            v[m] = a - b;
        }

#pragma unroll
        for (int k = 0; k < NF; ++k) {
            double re = (k & 1) ? (y0 - y15) : (y0 + y15);
            double im = 0.0;
#pragma unroll
            for (int m = 1; m < 15; ++m) {
                const double tcv = TC[(k * m) % 30];
                const double tsv = TS[(k * m) % 30];
                re += u[m] * tcv;
                if (tsv != 0.0) im += v[m] * tsv;
            }
            double pw = re * re + im * im;
            pw *= INV_WN;
            if (k != 0 && k != NF - 1) pw = pw + pw;
            psd[k] += pw;
        }
    }
#pragma unroll
    for (int k = 0; k < NF; ++k) psd[k] = psd[k] * THIRD;

    // ---- spectral features, f64 ----
    double total = np_sum16_f64(psd) + 1e-12;
    double invt = 1.0 / total;

    double band1 = psd[1] * invt;
    double band3 = ((psd[2] + psd[3]) + psd[4]) * invt;
    double b4s = 0.0;
#pragma unroll
    for (int k = 5; k <= 14; ++k) b4s += psd[k];
    double band4 = b4s * invt;

    int bk = 0; double bpv = psd[0];
#pragma unroll
    for (int k = 1; k < NF; ++k) if (psd[k] > bpv) { bpv = psd[k]; bk = k; }

    double th = 0.95 * total;
    int ek = 0;
    {
        double acc = 0.0; bool found = false;
#pragma unroll
        for (int k = 0; k < NF; ++k) {
            acc += psd[k];
            if (!found && acc >= th) { ek = k; found = true; }
        }
    }

    double ent = 0.0;
#pragma unroll
    for (int k = 0; k < NF; ++k) {
        double pn = psd[k] * invt;
        ent -= pn * log2(pn + 1e-12);
    }

    double spec[9];
    spec[0] = 0.0;
    spec[1] = band1;
    spec[2] = 0.0;
    spec[3] = band3;
    spec[4] = band4;
    spec[5] = (double)((float)((double)bk * 200.0 / 30.0));
    spec[6] = (double)((float)((double)ek * 200.0 / 30.0));
    spec[7] = ent;
    spec[8] = total;
#pragma unroll
    for (int i = 0; i < 9; ++i) if (!isfinite(spec[i])) spec[i] = 0.0;

    // spec group layernorm (f64) -> f[13..21]
    {
        double mu = 0.0;
#pragma unroll
        for (int i = 0; i < 9; ++i) mu += spec[i];
        mu /= 9.0;
        double var = 0.0;
#pragma unroll
        for (int i = 0; i < 9; ++i) { double d = spec[i] - mu; var += d * d; }
        var /= 9.0;
        double inv = 1.0 / sqrt(var + 1e-5);
#pragma unroll
        for (int i = 0; i < 9; ++i)
            f[13 + i] = (float)((spec[i] - mu) * inv * (double)g_s[i] + (double)b_s[i]);
    }

    // ---- block-compact feature store (contiguous within each 32-patch group) ----
    const int p = row * NP_ROW + tid;
    float* op = out + (size_t)(p >> 5) * (GB * 256) + (size_t)(p & 31) * 22;
#pragma unroll
    for (int i = 0; i < 11; ++i)
        *reinterpret_cast<float2*>(op + 2 * i) = make_float2(f[2 * i], f[2 * i + 1]);
}

// ===================== Kernel B: MLP (f32) =====================
// One block = 32 patches. Channel map ch = 4*(tid&63)+c so W2/b2/g_o/b_o/out
// are all float4 accesses. Wave wv owns patches 8*wv..8*wv+7 and all 256
// channels -> output layernorm is one in-wave shuffle reduction.
// (256,4): 128-VGPR cap vs ~100 needed -> no spill, 4 waves/SIMD.
// Per-accumulator k-order unchanged -> W2 GEMM bit-identical to verified.
__global__ __launch_bounds__(256, 4) void mlp_kernel(
    const float* __restrict__ W1, const float* __restrict__ b1,
    const float* __restrict__ W2, const float* __restrict__ b2,
    const float* __restrict__ g_o, const float* __restrict__ b_o,
    float* __restrict__ out)
{
    __shared__ float Fsl[GB * 22];     // 704 floats
    __shared__ float Hs[GB][128];

    const int tid = threadIdx.x;
    const size_t base = (size_t)blockIdx.x * (GB * 256);

    // stage this block's compact feature slab (176 float4 = 704 floats)
    if (tid < 176)
        reinterpret_cast<float4*>(Fsl)[tid] =
            *reinterpret_cast<const float4*>(out + base + 4 * (size_t)tid);
    __syncthreads();

    // ---- W1 + exact gelu -> Hs ----
    {
        const int hc  = tid & 127;
        const int ppb = tid >> 7;
        float w1c[22];
#pragma unroll
        for (int k = 0; k < 22; ++k) w1c[k] = W1[k * 128 + hc];
        const float b1v = b1[hc];
#pragma unroll
        for (int v = 0; v < 16; ++v) {
            const int pp = ppb + 2 * v;
            float a = b1v;
#pragma unroll
            for (int k = 0; k < 22; ++k) a += Fsl[pp * 22 + k] * w1c[k];
            Hs[pp][hc] = 0.5f * a * (1.0f + erff(a * 0.70710678118654752440f));
        }
    }
    __syncthreads();

    // ---- W2 GEMM: thread owns 4 consecutive channels x 8 patches ----
    const int cb = tid & 63;
    const int wv = tid >> 6;

    float4 acc[8];
    {
        const float4 b2v = *reinterpret_cast<const float4*>(b2 + 4 * cb);
#pragma unroll
        for (int p = 0; p < 8; ++p) acc[p] = b2v;
    }

#pragma unroll 2
    for (int k = 0; k < 128; k += 4) {
        float4 w0 = *reinterpret_cast<const float4*>(&W2[(k + 0) * 256 + 4 * cb]);
        float4 w1 = *reinterpret_cast<const float4*>(&W2[(k + 1) * 256 + 4 * cb]);
        float4 w2 = *reinterpret_cast<const float4*>(&W2[(k + 2) * 256 + 4 * cb]);
        float4 w3 = *reinterpret_cast<const float4*>(&W2[(k + 3) * 256 + 4 * cb]);
#pragma unroll
        for (int p = 0; p < 8; ++p) {
            const float4 h = *reinterpret_cast<const float4*>(&Hs[8 * wv + p][k]);
            // k-ascending FMA order per accumulator (bit-identical to verified)
            acc[p].x += h.x * w0.x; acc[p].y += h.x * w0.y;
            acc[p].z += h.x * w0.z; acc[p].w += h.x * w0.w;
            acc[p].x += h.y * w1.x; acc[p].y += h.y * w1.y;
            acc[p].z += h.y * w1.z; acc[p].w += h.y * w1.w;
            acc[p].x += h.z * w2.x; acc[p].y += h.z * w2.y;
            acc[p].z += h.z * w2.z; acc[p].w += h.z * w2.w;
            acc[p].x += h.w * w3.x; acc[p].y += h.w * w3.y;
            acc[p].z += h.w * w3.z; acc[p].w += h.w * w3.w;
        }
    }

    // ---- 256-ch layernorm: in-wave reduction, float4 store ----
    const float4 go4 = *reinterpret_cast<const float4*>(g_o + 4 * cb);
    const float4 bo4 = *reinterpret_cast<const float4*>(b_o + 4 * cb);
#pragma unroll
    for (int p = 0; p < 8; ++p) {
        float s = (acc[p].x + acc[p].y) + (acc[p].z + acc[p].w);
        float q = (acc[p].x * acc[p].x + acc[p].y * acc[p].y)
                + (acc[p].z * acc[p].z + acc[p].w * acc[p].w);
        for (int off = 32; off; off >>= 1) {
            s += __shfl_xor(s, off);
            q += __shfl_xor(q, off);
        }
        const float mu  = s * (1.0f / 256.0f);
        const float var = q * (1.0f / 256.0f) - mu * mu;
        const float inv = rsqrtf(var + 1e-5f);
        float4 o;
        o.x = (acc[p].x - mu) * inv * go4.x + bo4.x;
        o.y = (acc[p].y - mu) * inv * go4.y + bo4.y;
        o.z = (acc[p].z - mu) * inv * go4.z + bo4.z;
        o.w = (acc[p].w - mu) * inv * go4.w + bo4.w;
        *reinterpret_cast<float4*>(out + base + (size_t)(8 * wv + p) * 256 + 4 * cb) = o;
    }
}

extern "C" void kernel_launch(void* const* d_in, const int* in_sizes, int n_in,
                              void* d_out, int out_size, void* d_ws, size_t ws_size,
                              hipStream_t stream) {
    const float* x   = (const float*)d_in[0];
    const float* g_m = (const float*)d_in[1];
    const float* b_m = (const float*)d_in[2];
    const float* g_s = (const float*)d_in[3];
    const float* b_s = (const float*)d_in[4];
    const float* W1  = (const float*)d_in[5];
    const float* b1  = (const float*)d_in[6];
    const float* W2  = (const float*)d_in[7];
    const float* b2  = (const float*)d_in[8];
    const float* g_o = (const float*)d_in[9];
    const float* b_o = (const float*)d_in[10];
    float* out = (float*)d_out;

    feat_kernel<<<NBATCH, 256, 0, stream>>>(x, g_m, b_m, g_s, b_s, out);
    mlp_kernel<<<NBLK_B, 256, 0, stream>>>(W1, b1, W2, b2, g_o, b_o, out);
}

// Round 6
// 481.037 us; speedup vs baseline: 1.5435x; 1.0599x over previous
//
#include <hip/hip_runtime.h>
#include <math.h>

#define NPERSEG 30
#define STEPW 15
#define NSEG 3
#define NF 16
#define PATCH 60
#define STRIDE 30
#define NP_ROW 199
#define NBATCH 1024
#define T_LEN 6000
#define NPATCH_TOTAL (NBATCH * NP_ROW)   /* 203776 */
#define GB 32
#define NBLK_B (NPATCH_TOTAL / GB)       /* 6368 */

// f64 twiddles cos/sin(2*pi*m/30), correctly-rounded decimal literals.
constexpr double TC[30] = {
  1.0,
  0.97814760073380563793,
  0.91354545764260089550,
  0.80901699437494742410,
  0.66913060635885821383,
  0.5,
  0.30901699437494742410,
  0.10452846326765347140,
 -0.10452846326765347140,
 -0.30901699437494742410,
 -0.5,
 -0.66913060635885821383,
 -0.80901699437494742410,
 -0.91354545764260089550,
 -0.97814760073380563793,
 -1.0,
 -0.97814760073380563793,
 -0.91354545764260089550,
 -0.80901699437494742410,
 -0.66913060635885821383,
 -0.5,
 -0.30901699437494742410,
 -0.10452846326765347140,
  0.10452846326765347140,
  0.30901699437494742410,
  0.5,
  0.66913060635885821383,
  0.80901699437494742410,
  0.91354545764260089550,
  0.97814760073380563793,
};
constexpr double TS[30] = {
  0.0,
  0.20791169081775933710,
  0.40673664307580020775,
  0.58778525229247312917,
  0.74314482547739423501,
  0.86602540378443864676,
  0.95105651629515357212,
  0.99452189536827333692,
  0.99452189536827333692,
  0.95105651629515357212,
  0.86602540378443864676,
  0.74314482547739423501,
  0.58778525229247312917,
  0.40673664307580020775,
  0.20791169081775933710,
  0.0,
 -0.20791169081775933710,
 -0.40673664307580020775,
 -0.58778525229247312917,
 -0.74314482547739423501,
 -0.86602540378443864676,
 -0.95105651629515357212,
 -0.99452189536827333692,
 -0.99452189536827333692,
 -0.95105651629515357212,
 -0.86602540378443864676,
 -0.74314482547739423501,
 -0.58778525229247312917,
 -0.40673664307580020775,
 -0.20791169081775933710,
};
// WIN_NORM = 200 * sum(hann^2) = 2250 exactly (periodic hann, N=30).
constexpr double INV_WN = 1.0 / 2250.0;
constexpr double THIRD  = 1.0 / 3.0;

// numpy's pairwise f32 sum for n=30
__device__ __forceinline__ float np_sum30_f32(const float* a) {
    float r[8];
#pragma unroll
    for (int j = 0; j < 8; ++j) r[j] = a[j];
#pragma unroll
    for (int i = 8; i < 24; i += 8)
#pragma unroll
        for (int j = 0; j < 8; ++j) r[j] += a[i + j];
    float res = ((r[0] + r[1]) + (r[2] + r[3])) + ((r[4] + r[5]) + (r[6] + r[7]));
#pragma unroll
    for (int i = 24; i < 30; ++i) res += a[i];
    return res;
}

// numpy pairwise f64 sum for n=16
__device__ __forceinline__ double np_sum16_f64(const double* a) {
    double r[8];
#pragma unroll
    for (int j = 0; j < 8; ++j) r[j] = a[j] + a[8 + j];
    return ((r[0] + r[1]) + (r[2] + r[3])) + ((r[4] + r[5]) + (r[6] + r[7]));
}

// ===================== Kernel A: per-patch features (f64) =====================
// One block = one batch row, row staged in LDS (x fetched from HBM once).
// Register-diet version: morph streams pf from LDS in 2 fused passes (no 60-reg
// copy); DFT is m-streaming with k-split into two halves (re/im[8] f64 live at
// a time). Each psd bin is an m-ascending f64 chain — bit-identical to the
// round-0 verified kernel's summation order. No launch-bounds min (round-4
// lesson: VGPR caps => scratch spill catastrophe).
__global__ __launch_bounds__(256) void feat_kernel(
    const float* __restrict__ x,
    const float* __restrict__ g_m, const float* __restrict__ b_m,
    const float* __restrict__ g_s, const float* __restrict__ b_s,
    float* __restrict__ out)
{
    __shared__ float xs[T_LEN];

    const int tid = threadIdx.x;
    const int row = blockIdx.x;

    {
        const float4* src = reinterpret_cast<const float4*>(x + (size_t)row * T_LEN);
        float4* dst = reinterpret_cast<float4*>(xs);
        for (int i = tid; i < T_LEN / 4; i += 256) dst[i] = src[i];
    }
    __syncthreads();
    if (tid >= NP_ROW) return;

    const float* pf = xs + tid * STRIDE;
    const int p = row * NP_ROW + tid;
    float* op = out + (size_t)(p >> 5) * (GB * 256) + (size_t)(p & 31) * 22;

    // ---- morph: two fused streaming passes (values identical to verified) ----
    double morph[13];
    {
        // pass 1: max/min/sum, |argmax|, zero-cross, diff stats
        const float v0f = pf[0];
        const double v0 = (double)v0f;
        double vmax = v0, vmin = v0, vsum = v0;
        float aval = fabsf(v0f); int amax = 0;
        float sv0 = v0f + 1e-10f;
        int prev = (sv0 > 0.0f) - (sv0 < 0.0f);
        int zc = 0;
        double dmax = 0.0, dmin = 0.0, dabssum = 0.0;
        double vprev = v0;
#pragma unroll
        for (int n = 1; n < PATCH; ++n) {
            const float vf = pf[n];
            const double v = (double)vf;
            vmax = fmax(vmax, v); vmin = fmin(vmin, v); vsum += v;
            const float a = fabsf(vf);
            if (a > aval) { aval = a; amax = n; }
            const float sv = vf + 1e-10f;
            const int sg = (sv > 0.0f) - (sv < 0.0f);
            if (sg != prev) zc++;
            prev = sg;
            const double d = v - vprev;
            if (n == 1) { dmax = d; dmin = d; dabssum = fabs(d); }
            else { dmax = fmax(dmax, d); dmin = fmin(dmin, d); dabssum += fabs(d); }
            vprev = v;
        }
        const double vmean = vsum / 60.0;
        const double dabsmean = dabssum / 59.0;
        const double peak_loc = (double)((float)amax / 60.0f);
        const double zcf = (double)zc / 60.0;

        // pass 2: central moments + ssq (n-ascending, as verified)
        double s2 = 0.0, s3 = 0.0, s4 = 0.0, ssq = 0.0;
#pragma unroll
        for (int n = 0; n < PATCH; ++n) {
            const double v = (double)pf[n];
            const double c = v - vmean, c2 = c * c;
            s2 += c2; s3 += c2 * c; s4 += c2 * c2;
            ssq += v * v;
        }
        const double m2 = s2 / 60.0, m3 = s3 / 60.0, m4 = s4 / 60.0;
        const double vstd = sqrt(m2);
        const double kurt = m4 / (m2 * m2) - 3.0;
        const double skew = m3 / (m2 * sqrt(m2));

        morph[0] = vmax;  morph[1] = vmin;  morph[2] = vmax - vmin;
        morph[3] = vmean; morph[4] = vstd;  morph[5] = peak_loc;
        morph[6] = dmax;  morph[7] = dmin;  morph[8] = dabsmean;
        morph[9] = zcf;   morph[10] = ssq;  morph[11] = kurt; morph[12] = skew;
#pragma unroll
        for (int i = 0; i < 13; ++i) if (!isfinite(morph[i])) morph[i] = 0.0;
    }
    // morph group layernorm (f64) -> store 13 floats now (kills f[] liveness)
    {
        double mu = 0.0;
#pragma unroll
        for (int i = 0; i < 13; ++i) mu += morph[i];
        mu /= 13.0;
        double var = 0.0;
#pragma unroll
        for (int i = 0; i < 13; ++i) { double d = morph[i] - mu; var += d * d; }
        var /= 13.0;
        const double inv = 1.0 / sqrt(var + 1e-5);
        float fm[13];
#pragma unroll
        for (int i = 0; i < 13; ++i)
            fm[i] = (float)((morph[i] - mu) * inv * (double)g_m[i] + (double)b_m[i]);
#pragma unroll
        for (int i = 0; i < 6; ++i)
            *reinterpret_cast<float2*>(op + 2 * i) = make_float2(fm[2 * i], fm[2 * i + 1]);
        op[12] = fm[12];
    }

    // end morph liveness; DFT re-reads its slices from LDS
    asm volatile("" ::: "memory");

    // ---- Welch PSD: f32 windowing (verbatim), f64 m-streaming DFT.
    //      Per-k chains are m-ascending == bit-identical to round-0 order. ----
    double psd[NF];
#pragma unroll
    for (int k = 0; k < NF; ++k) psd[k] = 0.0;

#pragma unroll 1
    for (int s = 0; s < NSEG; ++s) {
        float y[NPERSEG];
        {
            float q[NPERSEG];
#pragma unroll
            for (int n = 0; n < NPERSEG; ++n) q[n] = pf[s * STEPW + n];
            const float res = np_sum30_f32(q);
            const float smean = res / 30.0f;
#pragma unroll
            for (int n = 0; n < NPERSEG; ++n) {
                const float hn = (float)(0.5 * (1.0 - TC[n]));
                y[n] = (q[n] - smean) * hn;
            }
        }

        // half 0: k = 0..7 (re/im[8] live => ~32 f64 regs)
        {
            double re[8], im[8];
#pragma unroll
            for (int j = 0; j < 8; ++j) { re[j] = 0.0; im[j] = 0.0; }
#pragma unroll
            for (int m = 0; m < NPERSEG; ++m) {
                const double yd = (double)y[m];
#pragma unroll
                for (int j = 0; j < 8; ++j) {
                    const double tcv = TC[(j * m) % 30];
                    const double tsv = TS[(j * m) % 30];
                    re[j] += yd * tcv;
                    if (tsv != 0.0) im[j] += yd * tsv;  // compile-time skip of exact zeros
                }
            }
#pragma unroll
            for (int j = 0; j < 8; ++j) {
                double pw = re[j] * re[j] + im[j] * im[j];
                pw *= INV_WN;
                if (j != 0) pw = pw + pw;          // ONESIDED (k=0 stays x1)
                psd[j] += pw;
            }
        }
        // half 1: k = 8..15
        {
            double re[8], im[8];
#pragma unroll
            for (int j = 0; j < 8; ++j) { re[j] = 0.0; im[j] = 0.0; }
#pragma unroll
            for (int m = 0; m < NPERSEG; ++m) {
                const double yd = (double)y[m];
#pragma unroll
                for (int j = 0; j < 8; ++j) {
                    const int k = 8 + j;
                    const double tcv = TC[(k * m) % 30];
                    const double tsv = TS[(k * m) % 30];
                    re[j] += yd * tcv;
                    if (tsv != 0.0) im[j] += yd * tsv;
                }
            }
#pragma unroll
            for (int j = 0; j < 8; ++j) {
                double pw = re[j] * re[j] + im[j] * im[j];
                pw *= INV_WN;
                if (j != 7) pw = pw + pw;          // ONESIDED (k=15 stays x1)
                psd[8 + j] += pw;
            }
        }
    }
#pragma unroll
    for (int k = 0; k < NF; ++k) psd[k] = psd[k] * THIRD;

    // ---- spectral features, f64 (identical to verified) ----
    const double total = np_sum16_f64(psd) + 1e-12;
    const double invt = 1.0 / total;

    const double band1 = psd[1] * invt;
    const double band3 = ((psd[2] + psd[3]) + psd[4]) * invt;
    double b4s = 0.0;
#pragma unroll
    for (int k = 5; k <= 14; ++k) b4s += psd[k];
    const double band4 = b4s * invt;

    int bk = 0; double bpv = psd[0];
#pragma unroll
    for (int k = 1; k < NF; ++k) if (psd[k] > bpv) { bpv = psd[k]; bk = k; }

    const double th = 0.95 * total;
    int ek = 0;
    {
        double acc = 0.0; bool found = false;
#pragma unroll
        for (int k = 0; k < NF; ++k) {
            acc += psd[k];
            if (!found && acc >= th) { ek = k; found = true; }
        }
    }

    double ent = 0.0;
#pragma unroll
    for (int k = 0; k < NF; ++k) {
        const double pn = psd[k] * invt;
        ent -= pn * log2(pn + 1e-12);
    }

    double spec[9];
    spec[0] = 0.0;
    spec[1] = band1;
    spec[2] = 0.0;
    spec[3] = band3;
    spec[4] = band4;
    spec[5] = (double)((float)((double)bk * 200.0 / 30.0));
    spec[6] = (double)((float)((double)ek * 200.0 / 30.0));
    spec[7] = ent;
    spec[8] = total;
#pragma unroll
    for (int i = 0; i < 9; ++i) if (!isfinite(spec[i])) spec[i] = 0.0;

    // spec group layernorm (f64) -> store 9 floats
    {
        double mu = 0.0;
#pragma unroll
        for (int i = 0; i < 9; ++i) mu += spec[i];
        mu /= 9.0;
        double var = 0.0;
#pragma unroll
        for (int i = 0; i < 9; ++i) { double d = spec[i] - mu; var += d * d; }
        var /= 9.0;
        const double inv = 1.0 / sqrt(var + 1e-5);
        float fs[9];
#pragma unroll
        for (int i = 0; i < 9; ++i)
            fs[i] = (float)((spec[i] - mu) * inv * (double)g_s[i] + (double)b_s[i]);
        op[13] = fs[0];
#pragma unroll
        for (int i = 0; i < 4; ++i)
            *reinterpret_cast<float2*>(op + 14 + 2 * i) = make_float2(fs[1 + 2 * i], fs[2 + 2 * i]);
    }
}

// ===================== Kernel B: MLP (f32) =====================
// One block = 32 patches. Wave wv covers patches 8*wv..8*wv+7, lane-half-split:
// half = lane>>5 owns patches pbase..pbase+3, each thread owns 8 consecutive
// channels (ch0 = (lane&31)*8). Hs ds_read_b128 has TWO addresses per wave
// (one per half) -> one instruction feeds 2 patches (2-way = free, m136),
// halving LDS-pipe ops vs round 5 (the measured bottleneck: 256 reads x 12cy =
// 127us of LDS pipe vs 85us FMA floor). W2 addresses identical across halves.
// Per-accumulator k-order (k ascending, kk 0..3) unchanged -> GEMM bit-identical.
__global__ __launch_bounds__(256, 4) void mlp_kernel(
    const float* __restrict__ W1, const float* __restrict__ b1,
    const float* __restrict__ W2, const float* __restrict__ b2,
    const float* __restrict__ g_o, const float* __restrict__ b_o,
    float* __restrict__ out)
{
    __shared__ float Fsl[GB * 22];     // 704 floats
    __shared__ float Hs[GB][128];

    const int tid = threadIdx.x;
    const size_t base = (size_t)blockIdx.x * (GB * 256);

    // stage this block's compact feature slab (176 float4 = 704 floats)
    if (tid < 176)
        reinterpret_cast<float4*>(Fsl)[tid] =
            *reinterpret_cast<const float4*>(out + base + 4 * (size_t)tid);
    __syncthreads();

    // ---- W1 + exact gelu -> Hs (unchanged from verified round 5) ----
    {
        const int hc  = tid & 127;
        const int ppb = tid >> 7;
        float w1c[22];
#pragma unroll
        for (int k = 0; k < 22; ++k) w1c[k] = W1[k * 128 + hc];
        const float b1v = b1[hc];
#pragma unroll
        for (int v = 0; v < 16; ++v) {
            const int pp = ppb + 2 * v;
            float a = b1v;
#pragma unroll
            for (int k = 0; k < 22; ++k) a += Fsl[pp * 22 + k] * w1c[k];
            Hs[pp][hc] = 0.5f * a * (1.0f + erff(a * 0.70710678118654752440f));
        }
    }
    __syncthreads();

    // ---- W2 GEMM: thread = 8 consecutive channels x 4 patches (half-split) ----
    const int lane  = tid & 63;
    const int wv    = tid >> 6;
    const int half  = lane >> 5;
    const int l5    = lane & 31;
    const int ch0   = l5 * 8;
    const int pbase = 8 * wv + 4 * half;

    float4 accA[4], accB[4];   // [pp] x (ch0..3, ch4..7)
    {
        const float4 b2lo = *reinterpret_cast<const float4*>(b2 + ch0);
        const float4 b2hi = *reinterpret_cast<const float4*>(b2 + ch0 + 4);
#pragma unroll
        for (int pp = 0; pp < 4; ++pp) { accA[pp] = b2lo; accB[pp] = b2hi; }
    }

#pragma unroll 2
    for (int k = 0; k < 128; k += 4) {
        float4 h[4];
#pragma unroll
        for (int pp = 0; pp < 4; ++pp)
            h[pp] = *reinterpret_cast<const float4*>(&Hs[pbase + pp][k]);  // 2 addrs/wave
        float4 wlo[4], whi[4];
#pragma unroll
        for (int kk = 0; kk < 4; ++kk) {
            wlo[kk] = *reinterpret_cast<const float4*>(&W2[(k + kk) * 256 + ch0]);
            whi[kk] = *reinterpret_cast<const float4*>(&W2[(k + kk) * 256 + ch0 + 4]);
        }
        // k-ascending FMA order per accumulator (bit-identical to verified)
#pragma unroll
        for (int kk = 0; kk < 4; ++kk) {
#pragma unroll
            for (int pp = 0; pp < 4; ++pp) {
                const float hv = (kk == 0) ? h[pp].x : (kk == 1) ? h[pp].y
                               : (kk == 2) ? h[pp].z : h[pp].w;
                accA[pp].x += hv * wlo[kk].x; accA[pp].y += hv * wlo[kk].y;
                accA[pp].z += hv * wlo[kk].z; accA[pp].w += hv * wlo[kk].w;
                accB[pp].x += hv * whi[kk].x; accB[pp].y += hv * whi[kk].y;
                accB[pp].z += hv * whi[kk].z; accB[pp].w += hv * whi[kk].w;
            }
        }
    }

    // ---- 256-ch layernorm: in-half shuffle reduction (offsets 16..1), store ----
    const float4 golo = *reinterpret_cast<const float4*>(g_o + ch0);
    const float4 gohi = *reinterpret_cast<const float4*>(g_o + ch0 + 4);
    const float4 bolo = *reinterpret_cast<const float4*>(b_o + ch0);
    const float4 bohi = *reinterpret_cast<const float4*>(b_o + ch0 + 4);
#pragma unroll
    for (int pp = 0; pp < 4; ++pp) {
        float s = ((accA[pp].x + accA[pp].y) + (accA[pp].z + accA[pp].w))
                + ((accB[pp].x + accB[pp].y) + (accB[pp].z + accB[pp].w));
        float q = ((accA[pp].x * accA[pp].x + accA[pp].y * accA[pp].y)
                +  (accA[pp].z * accA[pp].z + accA[pp].w * accA[pp].w))
                + ((accB[pp].x * accB[pp].x + accB[pp].y * accB[pp].y)
                +  (accB[pp].z * accB[pp].z + accB[pp].w * accB[pp].w));
        for (int off = 16; off; off >>= 1) {   // xor of bits<5 stays inside the half
            s += __shfl_xor(s, off);
            q += __shfl_xor(q, off);
        }
        const float mu  = s * (1.0f / 256.0f);
        const float var = q * (1.0f / 256.0f) - mu * mu;
        const float inv = rsqrtf(var + 1e-5f);
        float4 oA, oB;
        oA.x = (accA[pp].x - mu) * inv * golo.x + bolo.x;
        oA.y = (accA[pp].y - mu) * inv * golo.y + bolo.y;
        oA.z = (accA[pp].z - mu) * inv * golo.z + bolo.z;
        oA.w = (accA[pp].w - mu) * inv * golo.w + bolo.w;
        oB.x = (accB[pp].x - mu) * inv * gohi.x + bohi.x;
        oB.y = (accB[pp].y - mu) * inv * gohi.y + bohi.y;
        oB.z = (accB[pp].z - mu) * inv * gohi.z + bohi.z;
        oB.w = (accB[pp].w - mu) * inv * gohi.w + bohi.w;
        float* orow = out + base + (size_t)(pbase + pp) * 256 + ch0;
        *reinterpret_cast<float4*>(orow)     = oA;
        *reinterpret_cast<float4*>(orow + 4) = oB;
    }
}

extern "C" void kernel_launch(void* const* d_in, const int* in_sizes, int n_in,
                              void* d_out, int out_size, void* d_ws, size_t ws_size,
                              hipStream_t stream) {
    const float* x   = (const float*)d_in[0];
    const float* g_m = (const float*)d_in[1];
    const float* b_m = (const float*)d_in[2];
    const float* g_s = (const float*)d_in[3];
    const float* b_s = (const float*)d_in[4];
    const float* W1  = (const float*)d_in[5];
    const float* b1  = (const float*)d_in[6];
    const float* W2  = (const float*)d_in[7];
    const float* b2  = (const float*)d_in[8];
    const float* g_o = (const float*)d_in[9];
    const float* b_o = (const float*)d_in[10];
    float* out = (float*)d_out;

    feat_kernel<<<NBATCH, 256, 0, stream>>>(x, g_m, b_m, g_s, b_s, out);
    mlp_kernel<<<NBLK_B, 256, 0, stream>>>(W1, b1, W2, b2, g_o, b_o, out);
}

// Round 7
// 443.682 us; speedup vs baseline: 1.6734x; 1.0842x over previous
//
#include <hip/hip_runtime.h>
#include <math.h>

#define NPERSEG 30
#define STEPW 15
#define NSEG 3
#define NF 16
#define PATCH 60
#define STRIDE 30
#define NP_ROW 199
#define NBATCH 1024
#define T_LEN 6000
#define NPATCH_TOTAL (NBATCH * NP_ROW)   /* 203776 */
#define GB 32
#define NBLK_B (NPATCH_TOTAL / GB)       /* 6368 */

// f64 twiddles cos/sin(2*pi*m/30), correctly-rounded decimal literals.
constexpr double TC[30] = {
  1.0,
  0.97814760073380563793,
  0.91354545764260089550,
  0.80901699437494742410,
  0.66913060635885821383,
  0.5,
  0.30901699437494742410,
  0.10452846326765347140,
 -0.10452846326765347140,
 -0.30901699437494742410,
 -0.5,
 -0.66913060635885821383,
 -0.80901699437494742410,
 -0.91354545764260089550,
 -0.97814760073380563793,
 -1.0,
 -0.97814760073380563793,
 -0.91354545764260089550,
 -0.80901699437494742410,
 -0.66913060635885821383,
 -0.5,
 -0.30901699437494742410,
 -0.10452846326765347140,
  0.10452846326765347140,
  0.30901699437494742410,
  0.5,
  0.66913060635885821383,
  0.80901699437494742410,
  0.91354545764260089550,
  0.97814760073380563793,
};
constexpr double TS[30] = {
  0.0,
  0.20791169081775933710,
  0.40673664307580020775,
  0.58778525229247312917,
  0.74314482547739423501,
  0.86602540378443864676,
  0.95105651629515357212,
  0.99452189536827333692,
  0.99452189536827333692,
  0.95105651629515357212,
  0.86602540378443864676,
  0.74314482547739423501,
  0.58778525229247312917,
  0.40673664307580020775,
  0.20791169081775933710,
  0.0,
 -0.20791169081775933710,
 -0.40673664307580020775,
 -0.58778525229247312917,
 -0.74314482547739423501,
 -0.86602540378443864676,
 -0.95105651629515357212,
 -0.99452189536827333692,
 -0.99452189536827333692,
 -0.95105651629515357212,
 -0.86602540378443864676,
 -0.74314482547739423501,
 -0.58778525229247312917,
 -0.40673664307580020775,
 -0.20791169081775933710,
};
// WIN_NORM = 200 * sum(hann^2) = 2250 exactly (periodic hann, N=30).
constexpr double INV_WN = 1.0 / 2250.0;
constexpr double THIRD  = 1.0 / 3.0;

// numpy's pairwise f32 sum for n=30
__device__ __forceinline__ float np_sum30_f32(const float* a) {
    float r[8];
#pragma unroll
    for (int j = 0; j < 8; ++j) r[j] = a[j];
#pragma unroll
    for (int i = 8; i < 24; i += 8)
#pragma unroll
        for (int j = 0; j < 8; ++j) r[j] += a[i + j];
    float res = ((r[0] + r[1]) + (r[2] + r[3])) + ((r[4] + r[5]) + (r[6] + r[7]));
#pragma unroll
    for (int i = 24; i < 30; ++i) res += a[i];
    return res;
}

// numpy pairwise f64 sum for n=16
__device__ __forceinline__ double np_sum16_f64(const double* a) {
    double r[8];
#pragma unroll
    for (int j = 0; j < 8; ++j) r[j] = a[j] + a[8 + j];
    return ((r[0] + r[1]) + (r[2] + r[3])) + ((r[4] + r[5]) + (r[6] + r[7]));
}

// ===================== Kernel A: per-patch features (f64) =====================
// One block = one batch row, row staged in LDS (x fetched from HBM once).
// DFT: m-streaming with the n<->30-n symmetry fold (u/v on the fly), k split in
// two 8-bin halves -> re/im[8] f64 live at a time, 420 f64 FMA/seg (half of r6).
// Per-bin chains: re = (y0 +/- y15) then += u[m]*TC m-ascending; im = 0 then
// += v[m]*TS (nonzero terms only) — EXACTLY the round-5 verified summation
// order (absmax 0.015625). No launch-bounds min (round-4 spill lesson).
__global__ __launch_bounds__(256) void feat_kernel(
    const float* __restrict__ x,
    const float* __restrict__ g_m, const float* __restrict__ b_m,
    const float* __restrict__ g_s, const float* __restrict__ b_s,
    float* __restrict__ out)
{
    __shared__ float xs[T_LEN];

    const int tid = threadIdx.x;
    const int row = blockIdx.x;

    {
        const float4* src = reinterpret_cast<const float4*>(x + (size_t)row * T_LEN);
        float4* dst = reinterpret_cast<float4*>(xs);
        for (int i = tid; i < T_LEN / 4; i += 256) dst[i] = src[i];
    }
    __syncthreads();
    if (tid >= NP_ROW) return;

    const float* pf = xs + tid * STRIDE;
    const int p = row * NP_ROW + tid;
    float* op = out + (size_t)(p >> 5) * (GB * 256) + (size_t)(p & 31) * 22;

    // ---- morph: two fused streaming passes (values identical to verified) ----
    double morph[13];
    {
        const float v0f = pf[0];
        const double v0 = (double)v0f;
        double vmax = v0, vmin = v0, vsum = v0;
        float aval = fabsf(v0f); int amax = 0;
        float sv0 = v0f + 1e-10f;
        int prev = (sv0 > 0.0f) - (sv0 < 0.0f);
        int zc = 0;
        double dmax = 0.0, dmin = 0.0, dabssum = 0.0;
        double vprev = v0;
#pragma unroll
        for (int n = 1; n < PATCH; ++n) {
            const float vf = pf[n];
            const double v = (double)vf;
            vmax = fmax(vmax, v); vmin = fmin(vmin, v); vsum += v;
            const float a = fabsf(vf);
            if (a > aval) { aval = a; amax = n; }
            const float sv = vf + 1e-10f;
            const int sg = (sv > 0.0f) - (sv < 0.0f);
            if (sg != prev) zc++;
            prev = sg;
            const double d = v - vprev;
            if (n == 1) { dmax = d; dmin = d; dabssum = fabs(d); }
            else { dmax = fmax(dmax, d); dmin = fmin(dmin, d); dabssum += fabs(d); }
            vprev = v;
        }
        const double vmean = vsum / 60.0;
        const double dabsmean = dabssum / 59.0;
        const double peak_loc = (double)((float)amax / 60.0f);
        const double zcf = (double)zc / 60.0;

        double s2 = 0.0, s3 = 0.0, s4 = 0.0, ssq = 0.0;
#pragma unroll
        for (int n = 0; n < PATCH; ++n) {
            const double v = (double)pf[n];
            const double c = v - vmean, c2 = c * c;
            s2 += c2; s3 += c2 * c; s4 += c2 * c2;
            ssq += v * v;
        }
        const double m2 = s2 / 60.0, m3 = s3 / 60.0, m4 = s4 / 60.0;
        const double vstd = sqrt(m2);
        const double kurt = m4 / (m2 * m2) - 3.0;
        const double skew = m3 / (m2 * sqrt(m2));

        morph[0] = vmax;  morph[1] = vmin;  morph[2] = vmax - vmin;
        morph[3] = vmean; morph[4] = vstd;  morph[5] = peak_loc;
        morph[6] = dmax;  morph[7] = dmin;  morph[8] = dabsmean;
        morph[9] = zcf;   morph[10] = ssq;  morph[11] = kurt; morph[12] = skew;
#pragma unroll
        for (int i = 0; i < 13; ++i) if (!isfinite(morph[i])) morph[i] = 0.0;
    }
    // morph group layernorm (f64) -> store 13 floats now (kills liveness)
    {
        double mu = 0.0;
#pragma unroll
        for (int i = 0; i < 13; ++i) mu += morph[i];
        mu /= 13.0;
        double var = 0.0;
#pragma unroll
        for (int i = 0; i < 13; ++i) { double d = morph[i] - mu; var += d * d; }
        var /= 13.0;
        const double inv = 1.0 / sqrt(var + 1e-5);
        float fm[13];
#pragma unroll
        for (int i = 0; i < 13; ++i)
            fm[i] = (float)((morph[i] - mu) * inv * (double)g_m[i] + (double)b_m[i]);
#pragma unroll
        for (int i = 0; i < 6; ++i)
            *reinterpret_cast<float2*>(op + 2 * i) = make_float2(fm[2 * i], fm[2 * i + 1]);
        op[12] = fm[12];
    }

    asm volatile("" ::: "memory");

    // ---- Welch PSD: f32 windowing (verbatim), f64 folded-streaming DFT ----
    double psd[NF];
#pragma unroll
    for (int k = 0; k < NF; ++k) psd[k] = 0.0;

#pragma unroll 1
    for (int s = 0; s < NSEG; ++s) {
        float y[NPERSEG];
        {
            float q[NPERSEG];
#pragma unroll
            for (int n = 0; n < NPERSEG; ++n) q[n] = pf[s * STEPW + n];
            const float res = np_sum30_f32(q);
            const float smean = res / 30.0f;
#pragma unroll
            for (int n = 0; n < NPERSEG; ++n) {
                const float hn = (float)(0.5 * (1.0 - TC[n]));
                y[n] = (q[n] - smean) * hn;
            }
        }
        const double y0d  = (double)y[0];
        const double y15d = (double)y[15];

        // half 0: k = 0..7
        {
            double re[8], im[8];
#pragma unroll
            for (int j = 0; j < 8; ++j) {
                re[j] = (j & 1) ? (y0d - y15d) : (y0d + y15d);  // k-parity init
                im[j] = 0.0;
            }
#pragma unroll
            for (int m = 1; m < 15; ++m) {
                const double u = (double)y[m] + (double)y[NPERSEG - m];
                const double v = (double)y[m] - (double)y[NPERSEG - m];
#pragma unroll
                for (int j = 0; j < 8; ++j) {
                    const double tcv = TC[(j * m) % 30];
                    const double tsv = TS[(j * m) % 30];
                    re[j] += u * tcv;
                    if (tsv != 0.0) im[j] += v * tsv;  // compile-time skip of zeros
                }
            }
#pragma unroll
            for (int j = 0; j < 8; ++j) {
                double pw = re[j] * re[j] + im[j] * im[j];
                pw *= INV_WN;
                if (j != 0) pw = pw + pw;              // ONESIDED (k=0 stays x1)
                psd[j] += pw;
            }
        }
        // half 1: k = 8..15
        {
            double re[8], im[8];
#pragma unroll
            for (int j = 0; j < 8; ++j) {
                re[j] = (j & 1) ? (y0d - y15d) : (y0d + y15d);  // (8+j)&1 == j&1
                im[j] = 0.0;
            }
#pragma unroll
            for (int m = 1; m < 15; ++m) {
                const double u = (double)y[m] + (double)y[NPERSEG - m];
                const double v = (double)y[m] - (double)y[NPERSEG - m];
#pragma unroll
                for (int j = 0; j < 8; ++j) {
                    const int k = 8 + j;
                    const double tcv = TC[(k * m) % 30];
                    const double tsv = TS[(k * m) % 30];
                    re[j] += u * tcv;
                    if (tsv != 0.0) im[j] += v * tsv;
                }
            }
#pragma unroll
            for (int j = 0; j < 8; ++j) {
                double pw = re[j] * re[j] + im[j] * im[j];
                pw *= INV_WN;
                if (j != 7) pw = pw + pw;              // ONESIDED (k=15 stays x1)
                psd[8 + j] += pw;
            }
        }
    }
#pragma unroll
    for (int k = 0; k < NF; ++k) psd[k] = psd[k] * THIRD;

    // ---- spectral features, f64 (identical to verified) ----
    const double total = np_sum16_f64(psd) + 1e-12;
    const double invt = 1.0 / total;

    const double band1 = psd[1] * invt;
    const double band3 = ((psd[2] + psd[3]) + psd[4]) * invt;
    double b4s = 0.0;
#pragma unroll
    for (int k = 5; k <= 14; ++k) b4s += psd[k];
    const double band4 = b4s * invt;

    int bk = 0; double bpv = psd[0];
#pragma unroll
    for (int k = 1; k < NF; ++k) if (psd[k] > bpv) { bpv = psd[k]; bk = k; }

    const double th = 0.95 * total;
    int ek = 0;
    {
        double acc = 0.0; bool found = false;
#pragma unroll
        for (int k = 0; k < NF; ++k) {
            acc += psd[k];
            if (!found && acc >= th) { ek = k; found = true; }
        }
    }

    double ent = 0.0;
#pragma unroll
    for (int k = 0; k < NF; ++k) {
        const double pn = psd[k] * invt;
        ent -= pn * log2(pn + 1e-12);
    }

    double spec[9];
    spec[0] = 0.0;
    spec[1] = band1;
    spec[2] = 0.0;
    spec[3] = band3;
    spec[4] = band4;
    spec[5] = (double)((float)((double)bk * 200.0 / 30.0));
    spec[6] = (double)((float)((double)ek * 200.0 / 30.0));
    spec[7] = ent;
    spec[8] = total;
#pragma unroll
    for (int i = 0; i < 9; ++i) if (!isfinite(spec[i])) spec[i] = 0.0;

    // spec group layernorm (f64) -> store 9 floats
    {
        double mu = 0.0;
#pragma unroll
        for (int i = 0; i < 9; ++i) mu += spec[i];
        mu /= 9.0;
        double var = 0.0;
#pragma unroll
        for (int i = 0; i < 9; ++i) { double d = spec[i] - mu; var += d * d; }
        var /= 9.0;
        const double inv = 1.0 / sqrt(var + 1e-5);
        float fs[9];
#pragma unroll
        for (int i = 0; i < 9; ++i)
            fs[i] = (float)((spec[i] - mu) * inv * (double)g_s[i] + (double)b_s[i]);
        op[13] = fs[0];
#pragma unroll
        for (int i = 0; i < 4; ++i)
            *reinterpret_cast<float2*>(op + 14 + 2 * i) = make_float2(fs[1 + 2 * i], fs[2 + 2 * i]);
    }
}

// ===================== Kernel B: MLP (f32) =====================
// Round-5 verified structure (228us, FMA-issue-bound at 41% occupancy), now at
// (256,8): VGPR cap 64 >= the 56 it naturally uses; 8 blocks/CU x 19456B =
// 155.6KB <= 160KB LDS -> 8 waves/SIMD for latency hiding.
// One block = 32 patches; thread owns 4 consecutive channels x 8 patches; wave
// wv owns patches 8wv..8wv+7 and all 256 ch -> in-wave LN shuffle reduction.
// Per-accumulator k-order unchanged -> W2 GEMM bit-identical to verified.
__global__ __launch_bounds__(256, 8) void mlp_kernel(
    const float* __restrict__ W1, const float* __restrict__ b1,
    const float* __restrict__ W2, const float* __restrict__ b2,
    const float* __restrict__ g_o, const float* __restrict__ b_o,
    float* __restrict__ out)
{
    __shared__ float Fsl[GB * 22];     // 704 floats
    __shared__ float Hs[GB][128];

    const int tid = threadIdx.x;
    const size_t base = (size_t)blockIdx.x * (GB * 256);

    // stage this block's compact feature slab (176 float4 = 704 floats)
    if (tid < 176)
        reinterpret_cast<float4*>(Fsl)[tid] =
            *reinterpret_cast<const float4*>(out + base + 4 * (size_t)tid);
    __syncthreads();

    // ---- W1 + exact gelu -> Hs ----
    {
        const int hc  = tid & 127;
        const int ppb = tid >> 7;
        float w1c[22];
#pragma unroll
        for (int k = 0; k < 22; ++k) w1c[k] = W1[k * 128 + hc];
        const float b1v = b1[hc];
#pragma unroll
        for (int v = 0; v < 16; ++v) {
            const int pp = ppb + 2 * v;
            float a = b1v;
#pragma unroll
            for (int k = 0; k < 22; ++k) a += Fsl[pp * 22 + k] * w1c[k];
            Hs[pp][hc] = 0.5f * a * (1.0f + erff(a * 0.70710678118654752440f));
        }
    }
    __syncthreads();

    // ---- W2 GEMM: thread owns 4 consecutive channels x 8 patches ----
    const int cb = tid & 63;
    const int wv = tid >> 6;

    float4 acc[8];
    {
        const float4 b2v = *reinterpret_cast<const float4*>(b2 + 4 * cb);
#pragma unroll
        for (int p = 0; p < 8; ++p) acc[p] = b2v;
    }

#pragma unroll 2
    for (int k = 0; k < 128; k += 4) {
        float4 w0 = *reinterpret_cast<const float4*>(&W2[(k + 0) * 256 + 4 * cb]);
        float4 w1 = *reinterpret_cast<const float4*>(&W2[(k + 1) * 256 + 4 * cb]);
        float4 w2 = *reinterpret_cast<const float4*>(&W2[(k + 2) * 256 + 4 * cb]);
        float4 w3 = *reinterpret_cast<const float4*>(&W2[(k + 3) * 256 + 4 * cb]);
#pragma unroll
        for (int p = 0; p < 8; ++p) {
            const float4 h = *reinterpret_cast<const float4*>(&Hs[8 * wv + p][k]);
            // k-ascending FMA order per accumulator (bit-identical to verified)
            acc[p].x += h.x * w0.x; acc[p].y += h.x * w0.y;
            acc[p].z += h.x * w0.z; acc[p].w += h.x * w0.w;
            acc[p].x += h.y * w1.x; acc[p].y += h.y * w1.y;
            acc[p].z += h.y * w1.z; acc[p].w += h.y * w1.w;
            acc[p].x += h.z * w2.x; acc[p].y += h.z * w2.y;
            acc[p].z += h.z * w2.z; acc[p].w += h.z * w2.w;
            acc[p].x += h.w * w3.x; acc[p].y += h.w * w3.y;
            acc[p].z += h.w * w3.z; acc[p].w += h.w * w3.w;
        }
    }

    // ---- 256-ch layernorm: in-wave reduction, float4 store ----
    const float4 go4 = *reinterpret_cast<const float4*>(g_o + 4 * cb);
    const float4 bo4 = *reinterpret_cast<const float4*>(b_o + 4 * cb);
#pragma unroll
    for (int p = 0; p < 8; ++p) {
        float s = (acc[p].x + acc[p].y) + (acc[p].z + acc[p].w);
        float q = (acc[p].x * acc[p].x + acc[p].y * acc[p].y)
                + (acc[p].z * acc[p].z + acc[p].w * acc[p].w);
        for (int off = 32; off; off >>= 1) {
            s += __shfl_xor(s, off);
            q += __shfl_xor(q, off);
        }
        const float mu  = s * (1.0f / 256.0f);
        const float var = q * (1.0f / 256.0f) - mu * mu;
        const float inv = rsqrtf(var + 1e-5f);
        float4 o;
        o.x = (acc[p].x - mu) * inv * go4.x + bo4.x;
        o.y = (acc[p].y - mu) * inv * go4.y + bo4.y;
        o.z = (acc[p].z - mu) * inv * go4.z + bo4.z;
        o.w = (acc[p].w - mu) * inv * go4.w + bo4.w;
        *reinterpret_cast<float4*>(out + base + (size_t)(8 * wv + p) * 256 + 4 * cb) = o;
    }
}

extern "C" void kernel_launch(void* const* d_in, const int* in_sizes, int n_in,
                              void* d_out, int out_size, void* d_ws, size_t ws_size,
                              hipStream_t stream) {
    const float* x   = (const float*)d_in[0];
    const float* g_m = (const float*)d_in[1];
    const float* b_m = (const float*)d_in[2];
    const float* g_s = (const float*)d_in[3];
    const float* b_s = (const float*)d_in[4];
    const float* W1  = (const float*)d_in[5];
    const float* b1  = (const float*)d_in[6];
    const float* W2  = (const float*)d_in[7];
    const float* b2  = (const float*)d_in[8];
    const float* g_o = (const float*)d_in[9];
    const float* b_o = (const float*)d_in[10];
    float* out = (float*)d_out;

    feat_kernel<<<NBATCH, 256, 0, stream>>>(x, g_m, b_m, g_s, b_s, out);
    mlp_kernel<<<NBLK_B, 256, 0, stream>>>(W1, b1, W2, b2, g_o, b_o, out);
}